// Round 2
// baseline (896.541 us; speedup 1.0000x reference)
//
#include <hip/hip_runtime.h>
#include <hip/hip_bf16.h>

#define HEADS 3

// ---------------------------------------------------------------- prep: ce[h] = sum_d We[h*D+d] * ae[h*D+d]
__global__ void prep_ce_kernel(const float* __restrict__ We1, const float* __restrict__ ae1,
                               const float* __restrict__ We2, const float* __restrict__ ae2,
                               const float* __restrict__ We3, const float* __restrict__ ae3,
                               float* __restrict__ ce) {
    int t = threadIdx.x;
    if (t >= 9) return;
    int l = t / 3, h = t % 3;
    const float* We = (l == 0) ? We1 : (l == 1) ? We2 : We3;
    const float* ae = (l == 0) ? ae1 : (l == 1) ? ae2 : ae3;
    int D = (l == 0) ? 8 : (l == 1) ? 16 : 32;
    float s = 0.f;
    for (int d = 0; d < D; d++) s += We[h * D + d] * ae[h * D + d];
    ce[t] = s;
}

// ---------------------------------------------------------------- CSR build
__global__ void hist_kernel(const int* __restrict__ dst, int* __restrict__ deg, int E) {
    int tid = blockIdx.x * blockDim.x + threadIdx.x;
    if (tid < E) atomicAdd(&deg[dst[tid]], 1);
}

__global__ void scan_kernel(const int* __restrict__ deg, int* __restrict__ row_ptr, int N) {
    __shared__ int sums[1024];
    int t = threadIdx.x;
    int C = (N + 1023) / 1024;
    int begi = t * C;
    int endi = begi + C; if (endi > N) endi = N;
    int s = 0;
    for (int i = begi; i < endi; i++) s += deg[i];
    sums[t] = s;
    __syncthreads();
    for (int off = 1; off < 1024; off <<= 1) {
        int v = (t >= off) ? sums[t - off] : 0;
        __syncthreads();
        sums[t] += v;
        __syncthreads();
    }
    int run = sums[t] - s;  // exclusive prefix of this chunk
    for (int i = begi; i < endi; i++) { row_ptr[i] = run; run += deg[i]; }
    if (t == 1023) row_ptr[N] = sums[1023];
}

// pack {src, ef} into one 8B record per edge
__global__ void scatter_kernel(const int* __restrict__ src, const int* __restrict__ dst,
                               const float* __restrict__ ef, const int* __restrict__ row_ptr,
                               int* __restrict__ cnt, int2* __restrict__ erec, int E) {
    int tid = blockIdx.x * blockDim.x + threadIdx.x;
    if (tid >= E) return;
    int d = dst[tid];
    int pos = row_ptr[d] + atomicAdd(&cnt[d], 1);
    int2 r;
    r.x = src[tid];
    r.y = __float_as_int(ef[tid]);
    erec[pos] = r;
}

// ---------------------------------------------------------------- node projection: ft, el, er
template <int FIN, int D, bool MEAN_PREV>
__launch_bounds__(256)
__global__ void node_kernel(const float* __restrict__ xin,
                            const float* __restrict__ W,
                            const float* __restrict__ al,
                            const float* __restrict__ ar,
                            float* __restrict__ ft,
                            float* __restrict__ el, float* __restrict__ er,
                            int N) {
    int tid = blockIdx.x * blockDim.x + threadIdx.x;
    if (tid >= N * HEADS) return;
    int n = tid / HEADS, h = tid % HEADS;
    float x[FIN];
    if (MEAN_PREV) {
        #pragma unroll
        for (int k = 0; k < FIN; k++)
            x[k] = (xin[(n * HEADS + 0) * FIN + k] +
                    xin[(n * HEADS + 1) * FIN + k] +
                    xin[(n * HEADS + 2) * FIN + k]) * (1.0f / 3.0f);
    } else {
        #pragma unroll
        for (int k = 0; k < FIN; k++) x[k] = xin[n * FIN + k];
    }
    float e_l = 0.f, e_r = 0.f;
    #pragma unroll
    for (int d = 0; d < D; d++) {
        const float* wr = &W[(h * D + d) * FIN];
        float f = 0.f;
        #pragma unroll
        for (int k = 0; k < FIN; k++) f += x[k] * wr[k];
        ft[(n * HEADS + h) * D + d] = f;
        e_l += f * al[h * D + d];
        e_r += f * ar[h * D + d];
    }
    el[tid] = e_l;
    er[tid] = e_r;
}

// ---------------------------------------------------------------- attention + aggregate
// 2 lanes per (node,head): each lane handles half the edges with single-pass
// online softmax, batched 4-wide; lane-pair combine via shfl_xor.
template <int D>
__launch_bounds__(256)
__global__ void agg_kernel(const int* __restrict__ row_ptr, const int2* __restrict__ erec,
                           const float* __restrict__ ft,
                           const float* __restrict__ el, const float* __restrict__ er,
                           const float* __restrict__ ce,   // [3] this layer
                           const float* __restrict__ b,    // [3*D]
                           float* __restrict__ out,        // [N,3,D]
                           int NH) {
    int gtid = blockIdx.x * blockDim.x + threadIdx.x;
    int unit = gtid >> 1;
    if (unit >= NH) return;
    int slice = gtid & 1;
    int n = unit / HEADS, h = unit - n * HEADS;
    int beg = row_ptr[n], end = row_ptr[n + 1];
    int cnt = end - beg;
    int half = (cnt + 1) >> 1;
    int es = beg + slice * half;
    int ee = slice ? end : (beg + half);

    float ern = er[unit];
    float ceh = ce[h];
    float m = -3.0e38f, ssum = 0.f;
    float msg[D];
    #pragma unroll
    for (int d = 0; d < D; d++) msg[d] = 0.f;

    int e = es;
    for (; e + 3 < ee; e += 4) {
        int2 r0 = erec[e + 0], r1 = erec[e + 1], r2 = erec[e + 2], r3 = erec[e + 3];
        float v0 = el[r0.x * HEADS + h] + ern + __int_as_float(r0.y) * ceh;
        float v1 = el[r1.x * HEADS + h] + ern + __int_as_float(r1.y) * ceh;
        float v2 = el[r2.x * HEADS + h] + ern + __int_as_float(r2.y) * ceh;
        float v3 = el[r3.x * HEADS + h] + ern + __int_as_float(r3.y) * ceh;
        v0 = v0 > 0.f ? v0 : 0.2f * v0;
        v1 = v1 > 0.f ? v1 : 0.2f * v1;
        v2 = v2 > 0.f ? v2 : 0.2f * v2;
        v3 = v3 > 0.f ? v3 : 0.2f * v3;
        float cm = fmaxf(fmaxf(v0, v1), fmaxf(v2, v3));
        if (cm > m) {
            float sc = __expf(m - cm);
            ssum *= sc;
            #pragma unroll
            for (int d = 0; d < D; d++) msg[d] *= sc;
            m = cm;
        }
        float x0 = __expf(v0 - m), x1 = __expf(v1 - m);
        float x2 = __expf(v2 - m), x3 = __expf(v3 - m);
        ssum += (x0 + x1) + (x2 + x3);
        const float* f0 = &ft[(r0.x * HEADS + h) * D];
        const float* f1 = &ft[(r1.x * HEADS + h) * D];
        const float* f2 = &ft[(r2.x * HEADS + h) * D];
        const float* f3 = &ft[(r3.x * HEADS + h) * D];
        #pragma unroll
        for (int q = 0; q < D; q += 4) {
            float4 a0 = *(const float4*)(f0 + q);
            float4 a1 = *(const float4*)(f1 + q);
            float4 a2 = *(const float4*)(f2 + q);
            float4 a3 = *(const float4*)(f3 + q);
            msg[q + 0] += x0 * a0.x + x1 * a1.x + x2 * a2.x + x3 * a3.x;
            msg[q + 1] += x0 * a0.y + x1 * a1.y + x2 * a2.y + x3 * a3.y;
            msg[q + 2] += x0 * a0.z + x1 * a1.z + x2 * a2.z + x3 * a3.z;
            msg[q + 3] += x0 * a0.w + x1 * a1.w + x2 * a2.w + x3 * a3.w;
        }
    }
    for (; e < ee; e++) {
        int2 r = erec[e];
        float v = el[r.x * HEADS + h] + ern + __int_as_float(r.y) * ceh;
        v = v > 0.f ? v : 0.2f * v;
        if (v > m) {
            float sc = __expf(m - v);
            ssum *= sc;
            #pragma unroll
            for (int d = 0; d < D; d++) msg[d] *= sc;
            m = v;
        }
        float x = __expf(v - m);
        ssum += x;
        const float* fr = &ft[(r.x * HEADS + h) * D];
        #pragma unroll
        for (int q = 0; q < D; q += 4) {
            float4 a = *(const float4*)(fr + q);
            msg[q + 0] += x * a.x;
            msg[q + 1] += x * a.y;
            msg[q + 2] += x * a.z;
            msg[q + 3] += x * a.w;
        }
    }

    // lane-pair combine (partner = lane ^ 1)
    float om = __shfl_xor(m, 1);
    float osum = __shfl_xor(ssum, 1);
    float M = fmaxf(m, om);
    float sA = __expf(m - M);
    float sB = __expf(om - M);
    float tot = ssum * sA + osum * sB;
    float inv = 1.0f / fmaxf(tot, 1e-9f);
    #pragma unroll
    for (int d = 0; d < D; d++)
        msg[d] = msg[d] * sA + __shfl_xor(msg[d], 1) * sB;

    // split the store: even lane writes first half, odd lane second half
    int lo = slice * (D / 2);
    int base = unit * D + lo;
    #pragma unroll
    for (int d = 0; d < D / 2; d += 4) {
        float4 v;
        v.x = msg[lo + d + 0] * inv + b[h * D + lo + d + 0];
        v.y = msg[lo + d + 1] * inv + b[h * D + lo + d + 1];
        v.z = msg[lo + d + 2] * inv + b[h * D + lo + d + 2];
        v.w = msg[lo + d + 3] * inv + b[h * D + lo + d + 3];
        *(float4*)&out[base + d] = v;
    }
}

// ---------------------------------------------------------------- MLP head + global max
__global__ void mlp_max_kernel(const float* __restrict__ h3,
                               const float* __restrict__ l1w, const float* __restrict__ l1b,
                               const float* __restrict__ l2w, const float* __restrict__ l2b,
                               const float* __restrict__ l3w, const float* __restrict__ l3b,
                               const float* __restrict__ l4w, const float* __restrict__ l4b,
                               unsigned int* __restrict__ maxkey, int N) {
    int tid = blockIdx.x * blockDim.x + threadIdx.x;
    float feat = -3.0e38f;
    if (tid < N) {
        float acc = l4b[0];
        #pragma unroll
        for (int h = 0; h < HEADS; h++) {
            const float* v = &h3[(tid * HEADS + h) * 32];
            float y1[16];
            #pragma unroll
            for (int i = 0; i < 16; i++) {
                float s = l1b[i];
                const float* w = &l1w[i * 32];
                #pragma unroll
                for (int k = 0; k < 32; k++) s += v[k] * w[k];
                y1[i] = s > 0.f ? s : 0.01f * s;
            }
            float y2[4];
            #pragma unroll
            for (int i = 0; i < 4; i++) {
                float s = l2b[i];
                const float* w = &l2w[i * 16];
                #pragma unroll
                for (int k = 0; k < 16; k++) s += y1[k] * w[k];
                y2[i] = s > 0.f ? s : 0.01f * s;
            }
            float y3 = l3b[0];
            #pragma unroll
            for (int k = 0; k < 4; k++) y3 += y2[k] * l3w[k];
            acc += y3 * l4w[h];
        }
        feat = acc;
    }
    #pragma unroll
    for (int off = 32; off > 0; off >>= 1)
        feat = fmaxf(feat, __shfl_down(feat, off));
    if ((threadIdx.x & 63) == 0) {
        unsigned int u = __float_as_uint(feat);
        unsigned int key = (u & 0x80000000u) ? ~u : (u | 0x80000000u);
        atomicMax(maxkey, key);
    }
}

__global__ void finalize_kernel(const unsigned int* __restrict__ maxkey, float* __restrict__ out) {
    unsigned int key = *maxkey;
    unsigned int u = (key & 0x80000000u) ? (key & 0x7FFFFFFFu) : ~key;
    out[0] = __uint_as_float(u);
}

// ----------------------------------------------------------------
extern "C" void kernel_launch(void* const* d_in, const int* in_sizes, int n_in,
                              void* d_out, int out_size, void* d_ws, size_t ws_size,
                              hipStream_t stream) {
    const float* node_feats = (const float*)d_in[0];
    const float* edge_feats = (const float*)d_in[1];
    const int* src = (const int*)d_in[2];
    const int* dst = (const int*)d_in[3];
    const float* W1  = (const float*)d_in[4];
    const float* We1 = (const float*)d_in[5];
    const float* al1 = (const float*)d_in[6];
    const float* ar1 = (const float*)d_in[7];
    const float* ae1 = (const float*)d_in[8];
    const float* b1  = (const float*)d_in[9];
    const float* W2  = (const float*)d_in[10];
    const float* We2 = (const float*)d_in[11];
    const float* al2 = (const float*)d_in[12];
    const float* ar2 = (const float*)d_in[13];
    const float* ae2 = (const float*)d_in[14];
    const float* b2  = (const float*)d_in[15];
    const float* W3  = (const float*)d_in[16];
    const float* We3 = (const float*)d_in[17];
    const float* al3 = (const float*)d_in[18];
    const float* ar3 = (const float*)d_in[19];
    const float* ae3 = (const float*)d_in[20];
    const float* b3  = (const float*)d_in[21];
    const float* l1w = (const float*)d_in[22];
    const float* l1b = (const float*)d_in[23];
    const float* l2w = (const float*)d_in[24];
    const float* l2b = (const float*)d_in[25];
    const float* l3w = (const float*)d_in[26];
    const float* l3b = (const float*)d_in[27];
    const float* l4w = (const float*)d_in[28];
    const float* l4b = (const float*)d_in[29];

    const int N = in_sizes[0] / 6;
    const int E = in_sizes[2];

    char* ws = (char*)d_ws;
    size_t off = 0;
    auto alloc = [&](size_t bytes) -> void* {
        void* p = ws + off;
        off = (off + bytes + 255) & ~(size_t)255;
        return p;
    };
    int* deg            = (int*)alloc((size_t)N * 4);
    int* cnt            = (int*)alloc((size_t)N * 4);
    unsigned int* mkey  = (unsigned int*)alloc(4);
    size_t zero_bytes   = off;  // deg + cnt + maxkey
    int* row_ptr        = (int*)alloc((size_t)(N + 1) * 4);
    int2* erec          = (int2*)alloc((size_t)E * 8);
    float* ft           = (float*)alloc((size_t)N * 96 * 4);
    float* outb         = (float*)alloc((size_t)N * 96 * 4);
    float* el           = (float*)alloc((size_t)N * 3 * 4);
    float* er           = (float*)alloc((size_t)N * 3 * 4);
    float* ce           = (float*)alloc(9 * 4);

    hipMemsetAsync(d_ws, 0, zero_bytes, stream);

    prep_ce_kernel<<<1, 16, 0, stream>>>(We1, ae1, We2, ae2, We3, ae3, ce);
    hist_kernel<<<(E + 255) / 256, 256, 0, stream>>>(dst, deg, E);
    scan_kernel<<<1, 1024, 0, stream>>>(deg, row_ptr, N);
    scatter_kernel<<<(E + 255) / 256, 256, 0, stream>>>(src, dst, edge_feats, row_ptr, cnt,
                                                        erec, E);

    const int NH = N * HEADS;
    const int gb_node = (NH + 255) / 256;
    const int gb_agg  = (2 * NH + 255) / 256;

    // layer 1: 6 -> 8
    node_kernel<6, 8, false><<<gb_node, 256, 0, stream>>>(node_feats, W1, al1, ar1, ft, el, er, N);
    agg_kernel<8><<<gb_agg, 256, 0, stream>>>(row_ptr, erec, ft, el, er, ce + 0, b1, outb, NH);
    // layer 2: mean(8) -> 16
    node_kernel<8, 16, true><<<gb_node, 256, 0, stream>>>(outb, W2, al2, ar2, ft, el, er, N);
    agg_kernel<16><<<gb_agg, 256, 0, stream>>>(row_ptr, erec, ft, el, er, ce + 3, b2, outb, NH);
    // layer 3: mean(16) -> 32
    node_kernel<16, 32, true><<<gb_node, 256, 0, stream>>>(outb, W3, al3, ar3, ft, el, er, N);
    agg_kernel<32><<<gb_agg, 256, 0, stream>>>(row_ptr, erec, ft, el, er, ce + 6, b3, outb, NH);

    // MLP head + global max
    mlp_max_kernel<<<(N + 255) / 256, 256, 0, stream>>>(outb, l1w, l1b, l2w, l2b, l3w, l3b,
                                                        l4w, l4b, mkey, N);
    finalize_kernel<<<1, 1, 0, stream>>>(mkey, (float*)d_out);
}

// Round 3
// 523.925 us; speedup vs baseline: 1.7112x; 1.7112x over previous
//
#include <hip/hip_runtime.h>
#include <hip/hip_bf16.h>
#include <hip/hip_fp16.h>

#define HEADS 3

union HU { uint4 u; __half2 h[4]; };

// ---------------------------------------------------------------- prep: ce[h] = sum_d We[h*D+d] * ae[h*D+d]
__global__ void prep_ce_kernel(const float* __restrict__ We1, const float* __restrict__ ae1,
                               const float* __restrict__ We2, const float* __restrict__ ae2,
                               const float* __restrict__ We3, const float* __restrict__ ae3,
                               float* __restrict__ ce) {
    int t = threadIdx.x;
    if (t >= 9) return;
    int l = t / 3, h = t % 3;
    const float* We = (l == 0) ? We1 : (l == 1) ? We2 : We3;
    const float* ae = (l == 0) ? ae1 : (l == 1) ? ae2 : ae3;
    int D = (l == 0) ? 8 : (l == 1) ? 16 : 32;
    float s = 0.f;
    for (int d = 0; d < D; d++) s += We[h * D + d] * ae[h * D + d];
    ce[t] = s;
}

// ---------------------------------------------------------------- CSR build
__global__ void hist_kernel(const int* __restrict__ dst, int* __restrict__ deg, int E) {
    int tid = blockIdx.x * blockDim.x + threadIdx.x;
    if (tid < E) atomicAdd(&deg[dst[tid]], 1);
}

#define SCAN_BLK 1024
__global__ void scan1_kernel(const int* __restrict__ deg, int* __restrict__ row_ptr,
                             int* __restrict__ partials, int N) {
    __shared__ int sm[SCAN_BLK];
    int t = threadIdx.x;
    int g = blockIdx.x * SCAN_BLK + t;
    int v = (g < N) ? deg[g] : 0;
    sm[t] = v;
    __syncthreads();
    for (int off = 1; off < SCAN_BLK; off <<= 1) {
        int x = (t >= off) ? sm[t - off] : 0;
        __syncthreads();
        sm[t] += x;
        __syncthreads();
    }
    if (g < N) row_ptr[g] = sm[t] - v;   // exclusive
    if (t == SCAN_BLK - 1) partials[blockIdx.x] = sm[t];
}

__global__ void scan2_kernel(int* __restrict__ partials, int NB) {
    __shared__ int sm[128];
    int t = threadIdx.x;
    int v = (t < NB) ? partials[t] : 0;
    sm[t] = v;
    __syncthreads();
    for (int off = 1; off < 128; off <<= 1) {
        int x = (t >= off) ? sm[t - off] : 0;
        __syncthreads();
        sm[t] += x;
        __syncthreads();
    }
    if (t < NB) partials[t] = sm[t] - v;  // exclusive
    if (t == 127) partials[NB] = sm[127]; // total
}

__global__ void scan3_kernel(int* __restrict__ row_ptr, const int* __restrict__ partials,
                             int N, int NB) {
    int g = blockIdx.x * SCAN_BLK + threadIdx.x;
    if (g < N) row_ptr[g] += partials[blockIdx.x];
    if (blockIdx.x == 0 && threadIdx.x == 0) row_ptr[N] = partials[NB];
}

// pack {src, ef} into one 8B record per edge
__global__ void scatter_kernel(const int* __restrict__ src, const int* __restrict__ dst,
                               const float* __restrict__ ef, const int* __restrict__ row_ptr,
                               int* __restrict__ cnt, int2* __restrict__ erec, int E) {
    int tid = blockIdx.x * blockDim.x + threadIdx.x;
    if (tid >= E) return;
    int d = dst[tid];
    int pos = row_ptr[d] + atomicAdd(&cnt[d], 1);
    int2 r;
    r.x = src[tid];
    r.y = __float_as_int(ef[tid]);
    erec[pos] = r;
}

// ---------------------------------------------------------------- node projection: ft (fp16), el, er
template <int FIN, int D, bool MEAN_PREV>
__launch_bounds__(256)
__global__ void node_kernel(const float* __restrict__ xin,
                            const float* __restrict__ W,
                            const float* __restrict__ al,
                            const float* __restrict__ ar,
                            __half* __restrict__ ft,     // [N,3,D] fp16
                            float* __restrict__ el, float* __restrict__ er,
                            int N) {
    int tid = blockIdx.x * blockDim.x + threadIdx.x;
    if (tid >= N * HEADS) return;
    int n = tid / HEADS, h = tid % HEADS;
    float x[FIN];
    if (MEAN_PREV) {
        #pragma unroll
        for (int k = 0; k < FIN; k++)
            x[k] = (xin[(n * HEADS + 0) * FIN + k] +
                    xin[(n * HEADS + 1) * FIN + k] +
                    xin[(n * HEADS + 2) * FIN + k]) * (1.0f / 3.0f);
    } else {
        #pragma unroll
        for (int k = 0; k < FIN; k++) x[k] = xin[n * FIN + k];
    }
    float fv[D];
    float e_l = 0.f, e_r = 0.f;
    #pragma unroll
    for (int d = 0; d < D; d++) {
        const float* wr = &W[(h * D + d) * FIN];
        float f = 0.f;
        #pragma unroll
        for (int k = 0; k < FIN; k++) f += x[k] * wr[k];
        fv[d] = f;
        e_l += f * al[h * D + d];
        e_r += f * ar[h * D + d];
    }
    // packed fp16 store, 16B chunks
    uint4* dst16 = (uint4*)(ft + (size_t)tid * D);
    #pragma unroll
    for (int q = 0; q < D / 8; q++) {
        HU u;
        #pragma unroll
        for (int j = 0; j < 4; j++)
            u.h[j] = __floats2half2_rn(fv[q * 8 + 2 * j], fv[q * 8 + 2 * j + 1]);
        dst16[q] = u.u;
    }
    el[tid] = e_l;
    er[tid] = e_r;
}

// ---------------------------------------------------------------- attention + aggregate
// one thread per (node,head); single-pass online softmax; 4-edge batching; fp16 ft gather
template <int D>
__launch_bounds__(256)
__global__ void agg_kernel(const int* __restrict__ row_ptr, const int2* __restrict__ erec,
                           const __half* __restrict__ ft,
                           const float* __restrict__ el, const float* __restrict__ er,
                           const float* __restrict__ ce,   // [3] this layer
                           const float* __restrict__ b,    // [3*D]
                           float* __restrict__ out,        // [N,3,D]
                           int NH) {
    int unit = blockIdx.x * blockDim.x + threadIdx.x;
    if (unit >= NH) return;
    int n = unit / HEADS, h = unit - n * HEADS;
    int beg = row_ptr[n], end = row_ptr[n + 1];

    float ern = er[unit];
    float ceh = ce[h];
    float m = -3.0e38f, ssum = 0.f;
    float msg[D];
    #pragma unroll
    for (int d = 0; d < D; d++) msg[d] = 0.f;

    int e = beg;
    for (; e + 3 < end; e += 4) {
        int2 r0 = erec[e + 0], r1 = erec[e + 1], r2 = erec[e + 2], r3 = erec[e + 3];
        float v0 = el[r0.x * HEADS + h] + ern + __int_as_float(r0.y) * ceh;
        float v1 = el[r1.x * HEADS + h] + ern + __int_as_float(r1.y) * ceh;
        float v2 = el[r2.x * HEADS + h] + ern + __int_as_float(r2.y) * ceh;
        float v3 = el[r3.x * HEADS + h] + ern + __int_as_float(r3.y) * ceh;
        v0 = v0 > 0.f ? v0 : 0.2f * v0;
        v1 = v1 > 0.f ? v1 : 0.2f * v1;
        v2 = v2 > 0.f ? v2 : 0.2f * v2;
        v3 = v3 > 0.f ? v3 : 0.2f * v3;
        float cm = fmaxf(fmaxf(v0, v1), fmaxf(v2, v3));
        if (cm > m) {
            float sc = __expf(m - cm);
            ssum *= sc;
            #pragma unroll
            for (int d = 0; d < D; d++) msg[d] *= sc;
            m = cm;
        }
        float x0 = __expf(v0 - m), x1 = __expf(v1 - m);
        float x2 = __expf(v2 - m), x3 = __expf(v3 - m);
        ssum += (x0 + x1) + (x2 + x3);
        const uint4* f0 = (const uint4*)(ft + ((size_t)r0.x * HEADS + h) * D);
        const uint4* f1 = (const uint4*)(ft + ((size_t)r1.x * HEADS + h) * D);
        const uint4* f2 = (const uint4*)(ft + ((size_t)r2.x * HEADS + h) * D);
        const uint4* f3 = (const uint4*)(ft + ((size_t)r3.x * HEADS + h) * D);
        #pragma unroll
        for (int q = 0; q < D / 8; q++) {
            HU a0, a1, a2, a3;
            a0.u = f0[q]; a1.u = f1[q]; a2.u = f2[q]; a3.u = f3[q];
            #pragma unroll
            for (int j = 0; j < 4; j++) {
                float2 p0 = __half22float2(a0.h[j]);
                float2 p1 = __half22float2(a1.h[j]);
                float2 p2 = __half22float2(a2.h[j]);
                float2 p3 = __half22float2(a3.h[j]);
                msg[q * 8 + 2 * j + 0] += x0 * p0.x + x1 * p1.x + x2 * p2.x + x3 * p3.x;
                msg[q * 8 + 2 * j + 1] += x0 * p0.y + x1 * p1.y + x2 * p2.y + x3 * p3.y;
            }
        }
    }
    for (; e < end; e++) {
        int2 r = erec[e];
        float v = el[r.x * HEADS + h] + ern + __int_as_float(r.y) * ceh;
        v = v > 0.f ? v : 0.2f * v;
        if (v > m) {
            float sc = __expf(m - v);
            ssum *= sc;
            #pragma unroll
            for (int d = 0; d < D; d++) msg[d] *= sc;
            m = v;
        }
        float x = __expf(v - m);
        ssum += x;
        const uint4* fr = (const uint4*)(ft + ((size_t)r.x * HEADS + h) * D);
        #pragma unroll
        for (int q = 0; q < D / 8; q++) {
            HU a; a.u = fr[q];
            #pragma unroll
            for (int j = 0; j < 4; j++) {
                float2 p = __half22float2(a.h[j]);
                msg[q * 8 + 2 * j + 0] += x * p.x;
                msg[q * 8 + 2 * j + 1] += x * p.y;
            }
        }
    }

    float inv = 1.0f / fmaxf(ssum, 1e-9f);
    float4* ob = (float4*)(out + (size_t)unit * D);
    #pragma unroll
    for (int d = 0; d < D; d += 4) {
        float4 v;
        v.x = msg[d + 0] * inv + b[h * D + d + 0];
        v.y = msg[d + 1] * inv + b[h * D + d + 1];
        v.z = msg[d + 2] * inv + b[h * D + d + 2];
        v.w = msg[d + 3] * inv + b[h * D + d + 3];
        ob[d / 4] = v;
    }
}

// ---------------------------------------------------------------- MLP head + global max
__global__ void mlp_max_kernel(const float* __restrict__ h3,
                               const float* __restrict__ l1w, const float* __restrict__ l1b,
                               const float* __restrict__ l2w, const float* __restrict__ l2b,
                               const float* __restrict__ l3w, const float* __restrict__ l3b,
                               const float* __restrict__ l4w, const float* __restrict__ l4b,
                               unsigned int* __restrict__ maxkey, int N) {
    int tid = blockIdx.x * blockDim.x + threadIdx.x;
    float feat = -3.0e38f;
    if (tid < N) {
        float acc = l4b[0];
        #pragma unroll
        for (int h = 0; h < HEADS; h++) {
            const float4* vp = (const float4*)&h3[((size_t)tid * HEADS + h) * 32];
            float v[32];
            #pragma unroll
            for (int q = 0; q < 8; q++) {
                float4 t = vp[q];
                v[q * 4 + 0] = t.x; v[q * 4 + 1] = t.y; v[q * 4 + 2] = t.z; v[q * 4 + 3] = t.w;
            }
            float y1[16];
            #pragma unroll
            for (int i = 0; i < 16; i++) {
                float s = l1b[i];
                const float* w = &l1w[i * 32];
                #pragma unroll
                for (int k = 0; k < 32; k++) s += v[k] * w[k];
                y1[i] = s > 0.f ? s : 0.01f * s;
            }
            float y2[4];
            #pragma unroll
            for (int i = 0; i < 4; i++) {
                float s = l2b[i];
                const float* w = &l2w[i * 16];
                #pragma unroll
                for (int k = 0; k < 16; k++) s += y1[k] * w[k];
                y2[i] = s > 0.f ? s : 0.01f * s;
            }
            float y3 = l3b[0];
            #pragma unroll
            for (int k = 0; k < 4; k++) y3 += y2[k] * l3w[k];
            acc += y3 * l4w[h];
        }
        feat = acc;
    }
    #pragma unroll
    for (int off = 32; off > 0; off >>= 1)
        feat = fmaxf(feat, __shfl_down(feat, off));
    if ((threadIdx.x & 63) == 0) {
        unsigned int u = __float_as_uint(feat);
        unsigned int key = (u & 0x80000000u) ? ~u : (u | 0x80000000u);
        atomicMax(maxkey, key);
    }
}

__global__ void finalize_kernel(const unsigned int* __restrict__ maxkey, float* __restrict__ out) {
    unsigned int key = *maxkey;
    unsigned int u = (key & 0x80000000u) ? (key & 0x7FFFFFFFu) : ~key;
    out[0] = __uint_as_float(u);
}

// ----------------------------------------------------------------
extern "C" void kernel_launch(void* const* d_in, const int* in_sizes, int n_in,
                              void* d_out, int out_size, void* d_ws, size_t ws_size,
                              hipStream_t stream) {
    const float* node_feats = (const float*)d_in[0];
    const float* edge_feats = (const float*)d_in[1];
    const int* src = (const int*)d_in[2];
    const int* dst = (const int*)d_in[3];
    const float* W1  = (const float*)d_in[4];
    const float* We1 = (const float*)d_in[5];
    const float* al1 = (const float*)d_in[6];
    const float* ar1 = (const float*)d_in[7];
    const float* ae1 = (const float*)d_in[8];
    const float* b1  = (const float*)d_in[9];
    const float* W2  = (const float*)d_in[10];
    const float* We2 = (const float*)d_in[11];
    const float* al2 = (const float*)d_in[12];
    const float* ar2 = (const float*)d_in[13];
    const float* ae2 = (const float*)d_in[14];
    const float* b2  = (const float*)d_in[15];
    const float* W3  = (const float*)d_in[16];
    const float* We3 = (const float*)d_in[17];
    const float* al3 = (const float*)d_in[18];
    const float* ar3 = (const float*)d_in[19];
    const float* ae3 = (const float*)d_in[20];
    const float* b3  = (const float*)d_in[21];
    const float* l1w = (const float*)d_in[22];
    const float* l1b = (const float*)d_in[23];
    const float* l2w = (const float*)d_in[24];
    const float* l2b = (const float*)d_in[25];
    const float* l3w = (const float*)d_in[26];
    const float* l3b = (const float*)d_in[27];
    const float* l4w = (const float*)d_in[28];
    const float* l4b = (const float*)d_in[29];

    const int N = in_sizes[0] / 6;
    const int E = in_sizes[2];
    const int NB = (N + SCAN_BLK - 1) / SCAN_BLK;

    char* ws = (char*)d_ws;
    size_t off = 0;
    auto alloc = [&](size_t bytes) -> void* {
        void* p = ws + off;
        off = (off + bytes + 255) & ~(size_t)255;
        return p;
    };
    int* deg            = (int*)alloc((size_t)N * 4);
    int* cnt            = (int*)alloc((size_t)N * 4);
    unsigned int* mkey  = (unsigned int*)alloc(4);
    size_t zero_bytes   = off;  // deg + cnt + maxkey
    int* row_ptr        = (int*)alloc((size_t)(N + 1) * 4);
    int* partials       = (int*)alloc((size_t)(NB + 1) * 4);
    int2* erec          = (int2*)alloc((size_t)E * 8);
    __half* ft          = (__half*)alloc((size_t)N * 96 * 2);
    float* outb         = (float*)alloc((size_t)N * 96 * 4);
    float* el           = (float*)alloc((size_t)N * 3 * 4);
    float* er           = (float*)alloc((size_t)N * 3 * 4);
    float* ce           = (float*)alloc(9 * 4);

    hipMemsetAsync(d_ws, 0, zero_bytes, stream);

    prep_ce_kernel<<<1, 16, 0, stream>>>(We1, ae1, We2, ae2, We3, ae3, ce);
    hist_kernel<<<(E + 255) / 256, 256, 0, stream>>>(dst, deg, E);
    scan1_kernel<<<NB, SCAN_BLK, 0, stream>>>(deg, row_ptr, partials, N);
    scan2_kernel<<<1, 128, 0, stream>>>(partials, NB);
    scan3_kernel<<<NB, SCAN_BLK, 0, stream>>>(row_ptr, partials, N, NB);
    scatter_kernel<<<(E + 255) / 256, 256, 0, stream>>>(src, dst, edge_feats, row_ptr, cnt,
                                                        erec, E);

    const int NH = N * HEADS;
    const int gb = (NH + 255) / 256;

    // layer 1: 6 -> 8
    node_kernel<6, 8, false><<<gb, 256, 0, stream>>>(node_feats, W1, al1, ar1, ft, el, er, N);
    agg_kernel<8><<<gb, 256, 0, stream>>>(row_ptr, erec, ft, el, er, ce + 0, b1, outb, NH);
    // layer 2: mean(8) -> 16
    node_kernel<8, 16, true><<<gb, 256, 0, stream>>>(outb, W2, al2, ar2, ft, el, er, N);
    agg_kernel<16><<<gb, 256, 0, stream>>>(row_ptr, erec, ft, el, er, ce + 3, b2, outb, NH);
    // layer 3: mean(16) -> 32
    node_kernel<16, 32, true><<<gb, 256, 0, stream>>>(outb, W3, al3, ar3, ft, el, er, N);
    agg_kernel<32><<<gb, 256, 0, stream>>>(row_ptr, erec, ft, el, er, ce + 6, b3, outb, NH);

    // MLP head + global max
    mlp_max_kernel<<<(N + 255) / 256, 256, 0, stream>>>(outb, l1w, l1b, l2w, l2b, l3w, l3b,
                                                        l4w, l4b, mkey, N);
    finalize_kernel<<<1, 1, 0, stream>>>(mkey, (float*)d_out);
}

// Round 4
// 520.890 us; speedup vs baseline: 1.7212x; 1.0058x over previous
//
#include <hip/hip_runtime.h>
#include <hip/hip_bf16.h>
#include <hip/hip_fp16.h>

#define HEADS 3

union HU { uint4 u; __half2 h[4]; };

// ---------------------------------------------------------------- prep: ce[h] = sum_d We[h*D+d] * ae[h*D+d]
__global__ void prep_ce_kernel(const float* __restrict__ We1, const float* __restrict__ ae1,
                               const float* __restrict__ We2, const float* __restrict__ ae2,
                               const float* __restrict__ We3, const float* __restrict__ ae3,
                               float* __restrict__ ce) {
    int t = threadIdx.x;
    if (t >= 9) return;
    int l = t / 3, h = t % 3;
    const float* We = (l == 0) ? We1 : (l == 1) ? We2 : We3;
    const float* ae = (l == 0) ? ae1 : (l == 1) ? ae2 : ae3;
    int D = (l == 0) ? 8 : (l == 1) ? 16 : 32;
    float s = 0.f;
    for (int d = 0; d < D; d++) s += We[h * D + d] * ae[h * D + d];
    ce[t] = s;
}

// ---------------------------------------------------------------- CSR build
__global__ void hist_kernel(const int* __restrict__ dst, int* __restrict__ deg, int E) {
    int tid = blockIdx.x * blockDim.x + threadIdx.x;
    if (tid < E) atomicAdd(&deg[dst[tid]], 1);
}

#define SCAN_BLK 1024
__global__ void scan1_kernel(const int* __restrict__ deg, int* __restrict__ row_ptr,
                             int* __restrict__ partials, int N) {
    __shared__ int sm[SCAN_BLK];
    int t = threadIdx.x;
    int g = blockIdx.x * SCAN_BLK + t;
    int v = (g < N) ? deg[g] : 0;
    sm[t] = v;
    __syncthreads();
    for (int off = 1; off < SCAN_BLK; off <<= 1) {
        int x = (t >= off) ? sm[t - off] : 0;
        __syncthreads();
        sm[t] += x;
        __syncthreads();
    }
    if (g < N) row_ptr[g] = sm[t] - v;   // exclusive
    if (t == SCAN_BLK - 1) partials[blockIdx.x] = sm[t];
}

__global__ void scan2_kernel(int* __restrict__ partials, int NB) {
    __shared__ int sm[128];
    int t = threadIdx.x;
    int v = (t < NB) ? partials[t] : 0;
    sm[t] = v;
    __syncthreads();
    for (int off = 1; off < 128; off <<= 1) {
        int x = (t >= off) ? sm[t - off] : 0;
        __syncthreads();
        sm[t] += x;
        __syncthreads();
    }
    if (t < NB) partials[t] = sm[t] - v;  // exclusive
    if (t == 127) partials[NB] = sm[127]; // total
}

__global__ void scan3_kernel(int* __restrict__ row_ptr, const int* __restrict__ partials,
                             int N, int NB) {
    int g = blockIdx.x * SCAN_BLK + threadIdx.x;
    if (g < N) row_ptr[g] += partials[blockIdx.x];
    if (blockIdx.x == 0 && threadIdx.x == 0) row_ptr[N] = partials[NB];
}

// pack {src, ef} into one 8B record per edge
__global__ void scatter_kernel(const int* __restrict__ src, const int* __restrict__ dst,
                               const float* __restrict__ ef, const int* __restrict__ row_ptr,
                               int* __restrict__ cnt, int2* __restrict__ erec, int E) {
    int tid = blockIdx.x * blockDim.x + threadIdx.x;
    if (tid >= E) return;
    int d = dst[tid];
    int pos = row_ptr[d] + atomicAdd(&cnt[d], 1);
    int2 r;
    r.x = src[tid];
    r.y = __float_as_int(ef[tid]);
    erec[pos] = r;
}

// ---------------------------------------------------------------- node projection: ft (fp16), el, er
template <int FIN, int D, bool MEAN_PREV>
__launch_bounds__(256)
__global__ void node_kernel(const float* __restrict__ xin,
                            const float* __restrict__ W,
                            const float* __restrict__ al,
                            const float* __restrict__ ar,
                            __half* __restrict__ ft,     // [N,3,D] fp16
                            float* __restrict__ el, float* __restrict__ er,
                            int N) {
    int tid = blockIdx.x * blockDim.x + threadIdx.x;
    if (tid >= N * HEADS) return;
    int n = tid / HEADS, h = tid % HEADS;
    float x[FIN];
    if (MEAN_PREV) {
        #pragma unroll
        for (int k = 0; k < FIN; k++)
            x[k] = (xin[(n * HEADS + 0) * FIN + k] +
                    xin[(n * HEADS + 1) * FIN + k] +
                    xin[(n * HEADS + 2) * FIN + k]) * (1.0f / 3.0f);
    } else {
        #pragma unroll
        for (int k = 0; k < FIN; k++) x[k] = xin[n * FIN + k];
    }
    float fv[D];
    float e_l = 0.f, e_r = 0.f;
    #pragma unroll
    for (int d = 0; d < D; d++) {
        const float* wr = &W[(h * D + d) * FIN];
        float f = 0.f;
        #pragma unroll
        for (int k = 0; k < FIN; k++) f += x[k] * wr[k];
        fv[d] = f;
        e_l += f * al[h * D + d];
        e_r += f * ar[h * D + d];
    }
    // packed fp16 store, 16B chunks
    uint4* dst16 = (uint4*)(ft + (size_t)tid * D);
    #pragma unroll
    for (int q = 0; q < D / 8; q++) {
        HU u;
        #pragma unroll
        for (int j = 0; j < 4; j++)
            u.h[j] = __floats2half2_rn(fv[q * 8 + 2 * j], fv[q * 8 + 2 * j + 1]);
        dst16[q] = u.u;
    }
    el[tid] = e_l;
    er[tid] = e_r;
}

// ---------------------------------------------------------------- attention + aggregate
// 6 lanes per node: (slice s in {0,1}) x (head h in {0,1,2}), h innermost so the
// 3 head-lanes gather one contiguous ft node-group. 10 nodes per wave (lanes
// 60..63 idle). Single-pass online softmax per slice; slice-pair combine via shfl.
template <int D>
__launch_bounds__(256)
__global__ void agg_kernel(const int* __restrict__ row_ptr, const int2* __restrict__ erec,
                           const __half* __restrict__ ft,
                           const float* __restrict__ el, const float* __restrict__ er,
                           const float* __restrict__ ce,   // [3] this layer
                           const float* __restrict__ b,    // [3*D]
                           float* __restrict__ out,        // [N,3,D]
                           int N) {
    int w = threadIdx.x >> 6;
    int l = threadIdx.x & 63;
    int wl = l / 6;                 // node slot within wave, 0..9 (l>=60 idle)
    int rem = l - wl * 6;
    int s = rem >= 3 ? 1 : 0;
    int h = rem - s * 3;
    int n = (blockIdx.x * 4 + w) * 10 + wl;
    bool active = (wl < 10) && (n < N);

    float m = -3.0e38f, ssum = 0.f;
    float msg[D];
    #pragma unroll
    for (int d = 0; d < D; d++) msg[d] = 0.f;
    int unit = n * HEADS + h;
    float ceh = ce[h];

    if (active) {
        int beg = row_ptr[n], end = row_ptr[n + 1];
        int cnt = end - beg;
        int half = (cnt + 1) >> 1;
        int es = beg + s * half;
        int ee = s ? end : (beg + half);
        float ern = er[unit];

        int e = es;
        for (; e + 3 < ee; e += 4) {
            int2 r0 = erec[e + 0], r1 = erec[e + 1], r2 = erec[e + 2], r3 = erec[e + 3];
            float v0 = el[r0.x * HEADS + h] + ern + __int_as_float(r0.y) * ceh;
            float v1 = el[r1.x * HEADS + h] + ern + __int_as_float(r1.y) * ceh;
            float v2 = el[r2.x * HEADS + h] + ern + __int_as_float(r2.y) * ceh;
            float v3 = el[r3.x * HEADS + h] + ern + __int_as_float(r3.y) * ceh;
            v0 = v0 > 0.f ? v0 : 0.2f * v0;
            v1 = v1 > 0.f ? v1 : 0.2f * v1;
            v2 = v2 > 0.f ? v2 : 0.2f * v2;
            v3 = v3 > 0.f ? v3 : 0.2f * v3;
            float cm = fmaxf(fmaxf(v0, v1), fmaxf(v2, v3));
            if (cm > m) {
                float sc = __expf(m - cm);
                ssum *= sc;
                #pragma unroll
                for (int d = 0; d < D; d++) msg[d] *= sc;
                m = cm;
            }
            float x0 = __expf(v0 - m), x1 = __expf(v1 - m);
            float x2 = __expf(v2 - m), x3 = __expf(v3 - m);
            ssum += (x0 + x1) + (x2 + x3);
            const uint4* f0 = (const uint4*)(ft + ((size_t)r0.x * HEADS + h) * D);
            const uint4* f1 = (const uint4*)(ft + ((size_t)r1.x * HEADS + h) * D);
            const uint4* f2 = (const uint4*)(ft + ((size_t)r2.x * HEADS + h) * D);
            const uint4* f3 = (const uint4*)(ft + ((size_t)r3.x * HEADS + h) * D);
            #pragma unroll
            for (int q = 0; q < D / 8; q++) {
                HU a0, a1, a2, a3;
                a0.u = f0[q]; a1.u = f1[q]; a2.u = f2[q]; a3.u = f3[q];
                #pragma unroll
                for (int j = 0; j < 4; j++) {
                    float2 p0 = __half22float2(a0.h[j]);
                    float2 p1 = __half22float2(a1.h[j]);
                    float2 p2 = __half22float2(a2.h[j]);
                    float2 p3 = __half22float2(a3.h[j]);
                    msg[q * 8 + 2 * j + 0] += x0 * p0.x + x1 * p1.x + x2 * p2.x + x3 * p3.x;
                    msg[q * 8 + 2 * j + 1] += x0 * p0.y + x1 * p1.y + x2 * p2.y + x3 * p3.y;
                }
            }
        }
        for (; e < ee; e++) {
            int2 r = erec[e];
            float v = el[r.x * HEADS + h] + ern + __int_as_float(r.y) * ceh;
            v = v > 0.f ? v : 0.2f * v;
            if (v > m) {
                float sc = __expf(m - v);
                ssum *= sc;
                #pragma unroll
                for (int d = 0; d < D; d++) msg[d] *= sc;
                m = v;
            }
            float x = __expf(v - m);
            ssum += x;
            const uint4* fr = (const uint4*)(ft + ((size_t)r.x * HEADS + h) * D);
            #pragma unroll
            for (int q = 0; q < D / 8; q++) {
                HU a; a.u = fr[q];
                #pragma unroll
                for (int j = 0; j < 4; j++) {
                    float2 p = __half22float2(a.h[j]);
                    msg[q * 8 + 2 * j + 0] += x * p.x;
                    msg[q * 8 + 2 * j + 1] += x * p.y;
                }
            }
        }
    }

    // slice-pair combine: partner lane at +/-3
    int pl = (s ? (l - 3) : (l + 3)) & 63;
    float om = __shfl(m, pl);
    float osum = __shfl(ssum, pl);
    float M = fmaxf(m, om);
    float sA = __expf(m - M);
    float sB = __expf(om - M);
    float tot = ssum * sA + osum * sB;
    float inv = 1.0f / fmaxf(tot, 1e-9f);
    #pragma unroll
    for (int d = 0; d < D; d++)
        msg[d] = msg[d] * sA + __shfl(msg[d], pl) * sB;

    if (active) {
        // slice s stores its half of the output row
        int lo = s * (D / 2);
        float* ob = out + (size_t)unit * D + lo;
        #pragma unroll
        for (int d = 0; d < D / 2; d += 4) {
            float4 v;
            v.x = msg[lo + d + 0] * inv + b[h * D + lo + d + 0];
            v.y = msg[lo + d + 1] * inv + b[h * D + lo + d + 1];
            v.z = msg[lo + d + 2] * inv + b[h * D + lo + d + 2];
            v.w = msg[lo + d + 3] * inv + b[h * D + lo + d + 3];
            *(float4*)(ob + d) = v;
        }
    }
}

// ---------------------------------------------------------------- MLP head + global max
__global__ void mlp_max_kernel(const float* __restrict__ h3,
                               const float* __restrict__ l1w, const float* __restrict__ l1b,
                               const float* __restrict__ l2w, const float* __restrict__ l2b,
                               const float* __restrict__ l3w, const float* __restrict__ l3b,
                               const float* __restrict__ l4w, const float* __restrict__ l4b,
                               unsigned int* __restrict__ maxkey, int N) {
    int tid = blockIdx.x * blockDim.x + threadIdx.x;
    float feat = -3.0e38f;
    if (tid < N) {
        float acc = l4b[0];
        #pragma unroll
        for (int h = 0; h < HEADS; h++) {
            const float4* vp = (const float4*)&h3[((size_t)tid * HEADS + h) * 32];
            float v[32];
            #pragma unroll
            for (int q = 0; q < 8; q++) {
                float4 t = vp[q];
                v[q * 4 + 0] = t.x; v[q * 4 + 1] = t.y; v[q * 4 + 2] = t.z; v[q * 4 + 3] = t.w;
            }
            float y1[16];
            #pragma unroll
            for (int i = 0; i < 16; i++) {
                float s = l1b[i];
                const float* w = &l1w[i * 32];
                #pragma unroll
                for (int k = 0; k < 32; k++) s += v[k] * w[k];
                y1[i] = s > 0.f ? s : 0.01f * s;
            }
            float y2[4];
            #pragma unroll
            for (int i = 0; i < 4; i++) {
                float s = l2b[i];
                const float* w = &l2w[i * 16];
                #pragma unroll
                for (int k = 0; k < 16; k++) s += y1[k] * w[k];
                y2[i] = s > 0.f ? s : 0.01f * s;
            }
            float y3 = l3b[0];
            #pragma unroll
            for (int k = 0; k < 4; k++) y3 += y2[k] * l3w[k];
            acc += y3 * l4w[h];
        }
        feat = acc;
    }
    #pragma unroll
    for (int off = 32; off > 0; off >>= 1)
        feat = fmaxf(feat, __shfl_down(feat, off));
    if ((threadIdx.x & 63) == 0) {
        unsigned int u = __float_as_uint(feat);
        unsigned int key = (u & 0x80000000u) ? ~u : (u | 0x80000000u);
        atomicMax(maxkey, key);
    }
}

__global__ void finalize_kernel(const unsigned int* __restrict__ maxkey, float* __restrict__ out) {
    unsigned int key = *maxkey;
    unsigned int u = (key & 0x80000000u) ? (key & 0x7FFFFFFFu) : ~key;
    out[0] = __uint_as_float(u);
}

// ----------------------------------------------------------------
extern "C" void kernel_launch(void* const* d_in, const int* in_sizes, int n_in,
                              void* d_out, int out_size, void* d_ws, size_t ws_size,
                              hipStream_t stream) {
    const float* node_feats = (const float*)d_in[0];
    const float* edge_feats = (const float*)d_in[1];
    const int* src = (const int*)d_in[2];
    const int* dst = (const int*)d_in[3];
    const float* W1  = (const float*)d_in[4];
    const float* We1 = (const float*)d_in[5];
    const float* al1 = (const float*)d_in[6];
    const float* ar1 = (const float*)d_in[7];
    const float* ae1 = (const float*)d_in[8];
    const float* b1  = (const float*)d_in[9];
    const float* W2  = (const float*)d_in[10];
    const float* We2 = (const float*)d_in[11];
    const float* al2 = (const float*)d_in[12];
    const float* ar2 = (const float*)d_in[13];
    const float* ae2 = (const float*)d_in[14];
    const float* b2  = (const float*)d_in[15];
    const float* W3  = (const float*)d_in[16];
    const float* We3 = (const float*)d_in[17];
    const float* al3 = (const float*)d_in[18];
    const float* ar3 = (const float*)d_in[19];
    const float* ae3 = (const float*)d_in[20];
    const float* b3  = (const float*)d_in[21];
    const float* l1w = (const float*)d_in[22];
    const float* l1b = (const float*)d_in[23];
    const float* l2w = (const float*)d_in[24];
    const float* l2b = (const float*)d_in[25];
    const float* l3w = (const float*)d_in[26];
    const float* l3b = (const float*)d_in[27];
    const float* l4w = (const float*)d_in[28];
    const float* l4b = (const float*)d_in[29];

    const int N = in_sizes[0] / 6;
    const int E = in_sizes[2];
    const int NB = (N + SCAN_BLK - 1) / SCAN_BLK;

    char* ws = (char*)d_ws;
    size_t off = 0;
    auto alloc = [&](size_t bytes) -> void* {
        void* p = ws + off;
        off = (off + bytes + 255) & ~(size_t)255;
        return p;
    };
    int* deg            = (int*)alloc((size_t)N * 4);
    int* cnt            = (int*)alloc((size_t)N * 4);
    unsigned int* mkey  = (unsigned int*)alloc(4);
    size_t zero_bytes   = off;  // deg + cnt + maxkey
    int* row_ptr        = (int*)alloc((size_t)(N + 1) * 4);
    int* partials       = (int*)alloc((size_t)(NB + 1) * 4);
    int2* erec          = (int2*)alloc((size_t)E * 8);
    __half* ft          = (__half*)alloc((size_t)N * 96 * 2);
    float* outb         = (float*)alloc((size_t)N * 96 * 4);
    float* el           = (float*)alloc((size_t)N * 3 * 4);
    float* er           = (float*)alloc((size_t)N * 3 * 4);
    float* ce           = (float*)alloc(9 * 4);

    hipMemsetAsync(d_ws, 0, zero_bytes, stream);

    prep_ce_kernel<<<1, 16, 0, stream>>>(We1, ae1, We2, ae2, We3, ae3, ce);
    hist_kernel<<<(E + 255) / 256, 256, 0, stream>>>(dst, deg, E);
    scan1_kernel<<<NB, SCAN_BLK, 0, stream>>>(deg, row_ptr, partials, N);
    scan2_kernel<<<1, 128, 0, stream>>>(partials, NB);
    scan3_kernel<<<NB, SCAN_BLK, 0, stream>>>(row_ptr, partials, N, NB);
    scatter_kernel<<<(E + 255) / 256, 256, 0, stream>>>(src, dst, edge_feats, row_ptr, cnt,
                                                        erec, E);

    const int NH = N * HEADS;
    const int gb = (NH + 255) / 256;
    const int gb_agg = (N + 39) / 40;   // 40 nodes per 256-thread block

    // layer 1: 6 -> 8
    node_kernel<6, 8, false><<<gb, 256, 0, stream>>>(node_feats, W1, al1, ar1, ft, el, er, N);
    agg_kernel<8><<<gb_agg, 256, 0, stream>>>(row_ptr, erec, ft, el, er, ce + 0, b1, outb, N);
    // layer 2: mean(8) -> 16
    node_kernel<8, 16, true><<<gb, 256, 0, stream>>>(outb, W2, al2, ar2, ft, el, er, N);
    agg_kernel<16><<<gb_agg, 256, 0, stream>>>(row_ptr, erec, ft, el, er, ce + 3, b2, outb, N);
    // layer 3: mean(16) -> 32
    node_kernel<16, 32, true><<<gb, 256, 0, stream>>>(outb, W3, al3, ar3, ft, el, er, N);
    agg_kernel<32><<<gb_agg, 256, 0, stream>>>(row_ptr, erec, ft, el, er, ce + 6, b3, outb, N);

    // MLP head + global max
    mlp_max_kernel<<<(N + 255) / 256, 256, 0, stream>>>(outb, l1w, l1b, l2w, l2b, l3w, l3b,
                                                        l4w, l4b, mkey, N);
    finalize_kernel<<<1, 1, 0, stream>>>(mkey, (float*)d_out);
}